// Round 1
// baseline (229.021 us; speedup 1.0000x reference)
//
#include <hip/hip_runtime.h>
#include <hip/hip_bf16.h>

// InputAttention: B=256, T=128, F=1024, H=512
//   c[b,t]  = b1[t] + h[b,:]·W1[t,128:640] + s[b,:]·W1[t,640:1152]   (kernel A, fp32)
//   u[f,b,t]= sum_k x[b,k,f]*W1[t,k] + c[b,t]                        (kernel B, bf16 MFMA)
//   e[b,f]  = b2 + sum_t W2[t]*tanh(u)                               (kernel B epilogue)
//   out[b,f]= softmax_f(e[b,:])                                      (kernel C)

#define B_N 256
#define T_N 128
#define F_N 1024
#define H_N 512
#define IN1 1152

typedef __bf16 bf16x8 __attribute__((ext_vector_type(8)));
typedef float f32x16 __attribute__((ext_vector_type(16)));
typedef float f32x4_t __attribute__((ext_vector_type(4)));

__device__ __forceinline__ float wave_reduce_sum(float v) {
#pragma unroll
  for (int off = 32; off >= 1; off >>= 1) v += __shfl_xor(v, off, 64);
  return v;
}
__device__ __forceinline__ float wave_reduce_max(float v) {
#pragma unroll
  for (int off = 32; off >= 1; off >>= 1) v = fmaxf(v, __shfl_xor(v, off, 64));
  return v;
}

// ---------------- Kernel A: c[b,t] (fp32, exact) ----------------
// grid 2048 x 1024 thr. block = (tg 0..31, bg 0..63); wave w: t = tg*4 + (w>>2), b = bg*4 + (w&3).
__global__ __launch_bounds__(1024) void kA_c(const float* __restrict__ h,
                                             const float* __restrict__ s,
                                             const float* __restrict__ W1,
                                             const float* __restrict__ b1,
                                             float* __restrict__ c) {
  int tid = threadIdx.x;
  int lane = tid & 63, wid = tid >> 6;
  int tg = blockIdx.x >> 6;
  int bg = blockIdx.x & 63;
  int t = tg * 4 + (wid >> 2);
  int b = bg * 4 + (wid & 3);
  const float4* wrow = reinterpret_cast<const float4*>(W1 + t * IN1 + T_N);
  const float4* hrow = reinterpret_cast<const float4*>(h + b * H_N);
  const float4* srow = reinterpret_cast<const float4*>(s + b * H_N);
  float acc = 0.f;
#pragma unroll
  for (int i = 0; i < 4; ++i) {
    int j4 = i * 64 + lane;                       // float4 index over [h|s] (1024 floats)
    float4 w = wrow[j4];
    float4 v = (i < 2) ? hrow[j4] : srow[j4 - 128];
    acc += w.x * v.x + w.y * v.y + w.z * v.z + w.w * v.w;
  }
  acc = wave_reduce_sum(acc);
  if (lane == 0) c[b * T_N + t] = acc + b1[t];
}

// ---------------- Kernel A2: pack W1[:, :128] into bf16 MFMA A-fragments ----------------
// frag position p = ((tt*8+kk)*64 + lane)*8 + j  holds  W1[tt*32+(lane&31)][kk*16+8*(lane>>5)+j]
__global__ __launch_bounds__(256) void kA_frag(const float* __restrict__ W1,
                                               unsigned short* __restrict__ w1frag) {
  int i = blockIdx.x * 256 + threadIdx.x;  // 0..8191, 2 elems each
  int p0 = i * 2;
  int j = p0 & 7;
  int lane = (p0 >> 3) & 63;
  int kk = (p0 >> 9) & 7;
  int tt = (p0 >> 12) & 3;
  int t = tt * 32 + (lane & 31);
  int k = kk * 16 + 8 * (lane >> 5) + j;
  const float2 w = *reinterpret_cast<const float2*>(W1 + t * IN1 + k);
  __bf16 a = (__bf16)w.x, bq = (__bf16)w.y;
  unsigned short ua = __builtin_bit_cast(unsigned short, a);
  unsigned short ub = __builtin_bit_cast(unsigned short, bq);
  *reinterpret_cast<unsigned*>(w1frag + p0) = (unsigned)ua | ((unsigned)ub << 16);
}

// ---------------- Kernel B: e[b,f] via MFMA + tanh reduction ----------------
// grid 2048 x 256 thr (4 waves). block = (b = bid>>3, fg = bid&7); wave w owns f0 = fg*128 + w*32.
// Per wave: U[t=128, f=32] via 4 t-tiles x 8 k-steps of v_mfma_f32_32x32x16_bf16,
// A = W1tt (LDS fragments), B = x columns (direct global loads, f-contiguous dwords).
__global__ __launch_bounds__(256) void kB_e(const float* __restrict__ x,
                                            const unsigned short* __restrict__ w1frag,
                                            const float* __restrict__ c,
                                            const float* __restrict__ W2,
                                            const float* __restrict__ b2,
                                            float* __restrict__ e) {
  __shared__ __align__(16) unsigned short w1lds[16384];  // 32 KiB
  __shared__ __align__(16) float clds[T_N];
  __shared__ __align__(16) float w2lds[T_N];
  int tid = threadIdx.x;
  int b = blockIdx.x >> 3;
  int fg = blockIdx.x & 7;

  {  // stage fragment-ordered W1tt
    const uint4* src = reinterpret_cast<const uint4*>(w1frag);
    uint4* dst = reinterpret_cast<uint4*>(w1lds);
#pragma unroll
    for (int i = 0; i < 8; ++i) dst[tid + 256 * i] = src[tid + 256 * i];
  }
  if (tid < T_N) clds[tid] = c[b * T_N + tid];
  else if (tid < 2 * T_N) w2lds[tid - T_N] = W2[tid - T_N];
  __syncthreads();

  int lane = tid & 63, wave = tid >> 6;
  int g = lane >> 5, l31 = lane & 31;
  int f0 = fg * 128 + wave * 32;

  // B-fragment source: x[b][kk*16 + 8g + j][f0 + l31]
  const float* xb = x + (size_t)b * T_N * F_N + f0 + l31 + g * 8 * F_N;
  const bf16x8* af = reinterpret_cast<const bf16x8*>(w1lds);

  f32x16 acc0 = {}, acc1 = {}, acc2 = {}, acc3 = {};
#pragma unroll
  for (int kk = 0; kk < 8; ++kk) {
    float xv[8];
#pragma unroll
    for (int j = 0; j < 8; ++j) xv[j] = xb[(kk * 16 + j) * F_N];
    bf16x8 bfrag;
#pragma unroll
    for (int j = 0; j < 8; ++j) bfrag[j] = (__bf16)xv[j];
    int fidx = kk * 64 + lane;
    acc0 = __builtin_amdgcn_mfma_f32_32x32x16_bf16(af[fidx], bfrag, acc0, 0, 0, 0);
    acc1 = __builtin_amdgcn_mfma_f32_32x32x16_bf16(af[fidx + 512], bfrag, acc1, 0, 0, 0);
    acc2 = __builtin_amdgcn_mfma_f32_32x32x16_bf16(af[fidx + 1024], bfrag, acc2, 0, 0, 0);
    acc3 = __builtin_amdgcn_mfma_f32_32x32x16_bf16(af[fidx + 1536], bfrag, acc3, 0, 0, 0);
  }

  // epilogue: t = tt*32 + 4g + 8q + r  for reg = q*4+r  (C/D layout col=lane&31, row=(reg&3)+8*(reg>>2)+4*(lane>>5))
  float esum = 0.f;
#define EPI(ACC, TT)                                                              \
  {                                                                               \
    int bt = TT * 32 + 4 * g;                                                     \
    _Pragma("unroll") for (int q = 0; q < 4; ++q) {                               \
      f32x4_t cq = *reinterpret_cast<const f32x4_t*>(&clds[bt + 8 * q]);          \
      f32x4_t wq = *reinterpret_cast<const f32x4_t*>(&w2lds[bt + 8 * q]);         \
      _Pragma("unroll") for (int r = 0; r < 4; ++r) {                             \
        float u = ACC[q * 4 + r] + cq[r];                                         \
        u = fminf(fmaxf(u, -15.f), 15.f);                                         \
        float e2 = __expf(2.f * u);                                               \
        float th = (e2 - 1.f) / (e2 + 1.f);                                       \
        esum += wq[r] * th;                                                       \
      }                                                                           \
    }                                                                             \
  }
  EPI(acc0, 0) EPI(acc1, 1) EPI(acc2, 2) EPI(acc3, 3)
#undef EPI

  esum += __shfl_xor(esum, 32, 64);  // combine the two half-col groups (same f, rows split by g)
  if (g == 0) e[(size_t)b * F_N + f0 + l31] = esum + b2[0];
}

// ---------------- Kernel C: softmax over f per b, in-place on d_out ----------------
__global__ __launch_bounds__(256) void kC_softmax(float* __restrict__ out) {
  int b = blockIdx.x, tid = threadIdx.x;
  int lane = tid & 63, wid = tid >> 6;
  float* row = out + (size_t)b * F_N;
  float v[4];
#pragma unroll
  for (int q = 0; q < 4; ++q) v[q] = row[tid + 256 * q];
  float m = fmaxf(fmaxf(v[0], v[1]), fmaxf(v[2], v[3]));
  m = wave_reduce_max(m);
  __shared__ float rm[4], rs[4];
  if (lane == 0) rm[wid] = m;
  __syncthreads();
  float M = fmaxf(fmaxf(rm[0], rm[1]), fmaxf(rm[2], rm[3]));
  float ssum = 0.f;
#pragma unroll
  for (int q = 0; q < 4; ++q) {
    v[q] = __expf(v[q] - M);
    ssum += v[q];
  }
  ssum = wave_reduce_sum(ssum);
  if (lane == 0) rs[wid] = ssum;
  __syncthreads();
  float S = rs[0] + rs[1] + rs[2] + rs[3];
  float inv = 1.f / S;
#pragma unroll
  for (int q = 0; q < 4; ++q) row[tid + 256 * q] = v[q] * inv;
}

extern "C" void kernel_launch(void* const* d_in, const int* in_sizes, int n_in,
                              void* d_out, int out_size, void* d_ws, size_t ws_size,
                              hipStream_t stream) {
  const float* h = (const float*)d_in[0];
  const float* s = (const float*)d_in[1];
  const float* x = (const float*)d_in[2];
  const float* W1 = (const float*)d_in[3];
  const float* b1 = (const float*)d_in[4];
  const float* W2 = (const float*)d_in[5];
  const float* b2 = (const float*)d_in[6];
  float* out = (float*)d_out;

  float* c_ws = (float*)d_ws;                                          // 256*128*4 = 128 KiB
  unsigned short* w1frag = (unsigned short*)((char*)d_ws + B_N * T_N * 4);  // 32 KiB

  kA_c<<<2048, 1024, 0, stream>>>(h, s, W1, b1, c_ws);
  kA_frag<<<32, 256, 0, stream>>>(W1, w1frag);
  kB_e<<<2048, 256, 0, stream>>>(x, w1frag, c_ws, W2, b2, out);
  kC_softmax<<<256, 256, 0, stream>>>(out);
}